// Round 1
// baseline (1036.603 us; speedup 1.0000x reference)
//
#include <hip/hip_runtime.h>
#include <hip/hip_bf16.h>
#include <math.h>

// Problem constants
#define BATCH 64
#define CCH 64            // channels
#define K1 50
#define K2 25
#define K3 12
#define N1 (K1*K1)        // 2500
#define N2 (K2*K2)        // 625
#define N3 (K3*K3)        // 144
#define EPS_IN 1e-5f

__device__ __forceinline__ float readlane_f(float v, int l) {
    return __int_as_float(__builtin_amdgcn_readlane(__float_as_int(v), l));
}

__device__ __forceinline__ float celu1(float v) {
    return v > 0.f ? v : expm1f(v);
}

// ---------------------------------------------------------------------------
// Stage 0: h0[b,n,c] = agg[b,n] * w_init[c] + b_init[c]
// agg[b,n] = sum over 9-stencil of norm(src,dst) * x[b,src]
// grid: B*N1*64/256 blocks, 256 threads
// ---------------------------------------------------------------------------
__global__ __launch_bounds__(256) void stage0_kernel(
    const float* __restrict__ x, const float* __restrict__ w_init,
    const float* __restrict__ b_init, float* __restrict__ out)
{
    int e = blockIdx.x * 256 + threadIdx.x;
    int c = e & 63;
    int node = e >> 6;                 // b*N1 + n
    int b = node / N1, n = node - b * N1;
    int i = n / K1, j = n - i * K1;

    int di0 = (i > 0) ? -1 : 0, di1 = (i < K1-1) ? 1 : 0;
    int dj0 = (j > 0) ? -1 : 0, dj1 = (j < K1-1) ? 1 : 0;
    int degn = (di1 - di0 + 1) * (dj1 - dj0 + 1);

    float agg = 0.f;
    for (int di = di0; di <= di1; ++di) {
        for (int dj = dj0; dj <= dj1; ++dj) {
            int ii = i + di, jj = j + dj;
            int degnb = (1 + (ii > 0) + (ii < K1-1)) * (1 + (jj > 0) + (jj < K1-1));
            float wgt = 1.0f / sqrtf((float)(degn * degnb));
            agg = fmaf(wgt, x[b * N1 + ii * K1 + jj], agg);
        }
    }
    out[e] = fmaf(agg, w_init[c], b_init[c]);
}

// ---------------------------------------------------------------------------
// Fused GCNConv + InstanceNorm + (optional residual) + CELU.
// One wave per node, NPW nodes per wave. Lane = channel.
// W kept in 64 VGPRs per lane (column co=lane); stencil result s broadcast
// across lanes via v_readlane.
// ---------------------------------------------------------------------------
#define NPW 8
__global__ __launch_bounds__(256, 4) void conv_kernel(
    const float* __restrict__ xin, const float* __restrict__ resid,
    const float* __restrict__ Wm, const float* __restrict__ bias,
    float* __restrict__ out, int k, int N)
{
    int lane = threadIdx.x & 63;
    int w = threadIdx.x >> 6;

    float wreg[64];
#pragma unroll
    for (int ci = 0; ci < 64; ++ci) wreg[ci] = Wm[ci * 64 + lane];
    float bz = bias[lane];

    int base = blockIdx.x * (4 * NPW);
    for (int it = 0; it < NPW; ++it) {
        int node = base + it * 4 + w;       // exact grid: always valid
        int b = node / N, n = node - b * N;
        int i = n / k, j = n - i * k;

        int di0 = (i > 0) ? -1 : 0, di1 = (i < k-1) ? 1 : 0;
        int dj0 = (j > 0) ? -1 : 0, dj1 = (j < k-1) ? 1 : 0;
        int degn = (di1 - di0 + 1) * (dj1 - dj0 + 1);

        float s = 0.f;
        for (int di = di0; di <= di1; ++di) {
            for (int dj = dj0; dj <= dj1; ++dj) {
                int ii = i + di, jj = j + dj;
                int degnb = (1 + (ii > 0) + (ii < k-1)) * (1 + (jj > 0) + (jj < k-1));
                float wgt = 1.0f / sqrtf((float)(degn * degnb));
                s = fmaf(wgt, xin[(b * N + ii * k + jj) * 64 + lane], s);
            }
        }

        // 64x64 matmul: acc[co] = sum_ci s[ci] * W[ci][co]
        float acc = 0.f;
#pragma unroll
        for (int ci = 0; ci < 64; ++ci)
            acc = fmaf(readlane_f(s, ci), wreg[ci], acc);

        float t = acc + bz;

        // InstanceNorm over 64 channels (two-pass, matches jnp.var)
        float s1 = t;
#pragma unroll
        for (int off = 32; off; off >>= 1) s1 += __shfl_xor(s1, off, 64);
        float mean = s1 * (1.0f / 64.0f);
        float d = t - mean;
        float s2 = d * d;
#pragma unroll
        for (int off = 32; off; off >>= 1) s2 += __shfl_xor(s2, off, 64);
        float var = s2 * (1.0f / 64.0f);
        float val = d * (1.0f / sqrtf(var + EPS_IN));

        if (resid) val += resid[node * 64 + lane];
        out[node * 64 + lane] = celu1(val);
    }
}

// ---------------------------------------------------------------------------
// 2x2 max pool on k×k grid (truncating): out[b, pi*(k/2)+pj, c]
// grid: B*(k/2)^2*64 / 256
// ---------------------------------------------------------------------------
__global__ __launch_bounds__(256) void pool_kernel(
    const float* __restrict__ xin, float* __restrict__ out, int k, int Nin, int k2)
{
    int e = blockIdx.x * 256 + threadIdx.x;
    int c = e & 63;
    int np = e >> 6;
    int P = k2 * k2;
    int b = np / P, p = np - b * P;
    int pi = p / k2, pj = p - pi * k2;
    int base = (b * Nin + (2 * pi) * k + 2 * pj) * 64 + c;
    float v0 = xin[base];
    float v1 = xin[base + 64];
    float v2 = xin[base + k * 64];
    float v3 = xin[base + k * 64 + 64];
    out[e] = fmaxf(fmaxf(v0, v1), fmaxf(v2, v3));
}

// ---------------------------------------------------------------------------
// G = W W^T for W [256, K]. grid (8,8), block 256, 32x32 tile per block.
// ---------------------------------------------------------------------------
__global__ __launch_bounds__(256) void gram_kernel(
    const float* __restrict__ W, float* __restrict__ G, int K)
{
    __shared__ float As[32][33];
    __shared__ float Bs[32][33];
    int ti = blockIdx.x * 32;
    int tj = blockIdx.y * 32;
    int tx = threadIdx.x & 15, ty = threadIdx.x >> 4;
    float a00 = 0.f, a01 = 0.f, a10 = 0.f, a11 = 0.f;
    for (int k0 = 0; k0 < K; k0 += 32) {
        for (int l = threadIdx.x; l < 1024; l += 256) {
            int r = l >> 5, cc = l & 31;
            As[r][cc] = W[(ti + r) * K + k0 + cc];
            Bs[r][cc] = W[(tj + r) * K + k0 + cc];
        }
        __syncthreads();
#pragma unroll
        for (int kk = 0; kk < 32; ++kk) {
            float a0 = As[ty][kk],      a1 = As[ty + 16][kk];
            float b0 = Bs[tx][kk],      b1 = Bs[tx + 16][kk];
            a00 = fmaf(a0, b0, a00); a01 = fmaf(a0, b1, a01);
            a10 = fmaf(a1, b0, a10); a11 = fmaf(a1, b1, a11);
        }
        __syncthreads();
    }
    G[(ti + ty) * 256 + tj + tx]           = a00;
    G[(ti + ty) * 256 + tj + tx + 16]      = a01;
    G[(ti + ty + 16) * 256 + tj + tx]      = a10;
    G[(ti + ty + 16) * 256 + tj + tx + 16] = a11;
}

// ---------------------------------------------------------------------------
// Power iteration on G (256x256, symmetric): u <- normalize(G u) x29, then
// sigma = ||G u|| / sqrt(u . G u).  grid 2 (G1, G2), block 1024.
// Thread (i = tid&255, q = tid>>8) holds G[i, 64q..64q+63] in registers
// (loaded transposed via symmetry for coalescing).
// ---------------------------------------------------------------------------
__global__ __launch_bounds__(1024) void power_kernel(
    const float* __restrict__ G1, const float* __restrict__ G2,
    float* __restrict__ sig)
{
    const float* G = (blockIdx.x == 0) ? G1 : G2;
    __shared__ float u[256];
    __shared__ float red[1024];
    __shared__ float gu_s[256];
    __shared__ float nrm_s;
    int tid = threadIdx.x, i = tid & 255, q = tid >> 8;
    (void)i;

    float g[64];
#pragma unroll
    for (int m = 0; m < 64; ++m) g[m] = G[(q * 64 + m) * 256 + (tid & 255)];
    if (tid < 256) u[tid] = 0.0625f;   // 1/sqrt(256)
    __syncthreads();

    for (int it = 0; it < 29; ++it) {
        float p = 0.f;
#pragma unroll
        for (int m = 0; m < 64; ++m) p = fmaf(g[m], u[q * 64 + m], p);
        red[tid] = p;
        __syncthreads();
        if (tid < 256) {
            float gu = red[tid] + red[tid + 256] + red[tid + 512] + red[tid + 768];
            gu_s[tid] = gu;
        }
        __syncthreads();
        if (tid < 64) {
            float a = 0.f;
            for (int z = tid; z < 256; z += 64) { float v = gu_s[z]; a = fmaf(v, v, a); }
#pragma unroll
            for (int off = 32; off; off >>= 1) a += __shfl_xor(a, off, 64);
            if (tid == 0) nrm_s = a;
        }
        __syncthreads();
        if (tid < 256) {
            float rn = 1.0f / (sqrtf(nrm_s) + 1e-12f);
            u[tid] = gu_s[tid] * rn;
        }
        __syncthreads();
    }

    // final: a = ||G u||^2, b = u . (G u); sigma = sqrt(a/b)
    float p = 0.f;
#pragma unroll
    for (int m = 0; m < 64; ++m) p = fmaf(g[m], u[q * 64 + m], p);
    red[tid] = p;
    __syncthreads();
    if (tid < 256) {
        float gu = red[tid] + red[tid + 256] + red[tid + 512] + red[tid + 768];
        gu_s[tid] = gu;
    }
    __syncthreads();
    if (tid < 64) {
        float a = 0.f, bs = 0.f;
        for (int z = tid; z < 256; z += 64) {
            float v = gu_s[z];
            a = fmaf(v, v, a);
            bs = fmaf(u[z], v, bs);
        }
#pragma unroll
        for (int off = 32; off; off >>= 1) {
            a  += __shfl_xor(a, off, 64);
            bs += __shfl_xor(bs, off, 64);
        }
        if (tid == 0) sig[blockIdx.x] = sqrtf(a / bs);
    }
}

// ---------------------------------------------------------------------------
// out[b,o] = celu( dot(X[b,:], Wt[o,:]) / sigma + bias[o] )
// X [64,K], Wt [256,K]. grid (4 o-tiles, 4 b-tiles), block 256.
// Tile: 64 o x 16 b, K-chunks of 128 staged in LDS.
// ---------------------------------------------------------------------------
__global__ __launch_bounds__(256) void linear_kernel(
    const float* __restrict__ X, const float* __restrict__ Wt,
    const float* __restrict__ bias, const float* __restrict__ sig, int sidx,
    float* __restrict__ out, int K)
{
    __shared__ float wl[64 * 129];
    __shared__ float hl[16 * 128];
    int o0 = blockIdx.x * 64, b0 = blockIdx.y * 16;
    int t = threadIdx.x, o = t & 63, br = t >> 6;
    float acc[4] = {0.f, 0.f, 0.f, 0.f};

    for (int k0 = 0; k0 < K; k0 += 128) {
        for (int l = t; l < 64 * 128; l += 256) {
            int r = l >> 7, cc = l & 127;
            wl[r * 129 + cc] = Wt[(o0 + r) * K + k0 + cc];
        }
        for (int l = t; l < 16 * 128; l += 256) {
            int r = l >> 7, cc = l & 127;
            hl[r * 128 + cc] = X[(b0 + r) * K + k0 + cc];
        }
        __syncthreads();
        for (int kk = 0; kk < 128; ++kk) {
            float wv = wl[o * 129 + kk];
#pragma unroll
            for (int r = 0; r < 4; ++r)
                acc[r] = fmaf(hl[(br + (r << 2)) * 128 + kk], wv, acc[r]);
        }
        __syncthreads();
    }

    float is = 1.0f / sig[sidx];
    float bz = bias[o0 + o];
#pragma unroll
    for (int r = 0; r < 4; ++r) {
        float v = acc[r] * is + bz;
        out[(b0 + br + (r << 2)) * 256 + o0 + o] = celu1(v);
    }
}

// ---------------------------------------------------------------------------
extern "C" void kernel_launch(void* const* d_in, const int* in_sizes, int n_in,
                              void* d_out, int out_size, void* d_ws, size_t ws_size,
                              hipStream_t stream)
{
    const float* x      = (const float*)d_in[0];
    const float* w_init = (const float*)d_in[1];
    const float* b_init = (const float*)d_in[2];
    const float* w11 = (const float*)d_in[3];  const float* b11 = (const float*)d_in[4];
    const float* w12 = (const float*)d_in[5];  const float* b12 = (const float*)d_in[6];
    const float* w21 = (const float*)d_in[7];  const float* b21 = (const float*)d_in[8];
    const float* w22 = (const float*)d_in[9];  const float* b22 = (const float*)d_in[10];
    const float* w31 = (const float*)d_in[11]; const float* b31 = (const float*)d_in[12];
    const float* w32 = (const float*)d_in[13]; const float* b32 = (const float*)d_in[14];
    const float* lw1 = (const float*)d_in[15]; const float* lb1 = (const float*)d_in[16];
    const float* lw2 = (const float*)d_in[17]; const float* lb2 = (const float*)d_in[18];
    float* out = (float*)d_out;

    char* ws = (char*)d_ws;
    const size_t SZ_BIG = (size_t)BATCH * N1 * 64 * sizeof(float);   // 40,960,000 B
    float* A  = (float*)ws;
    float* Bb = (float*)(ws + SZ_BIG);
    float* Cb = (float*)(ws + 2 * SZ_BIG);
    float* G1 = (float*)(ws + 3 * SZ_BIG);
    float* G2 = G1 + 256 * 256;
    float* sg = G2 + 256 * 256;
    float* H1 = sg + 16;

    // Stage 0: init GCN  x -> A  [B, 2500, 64]
    stage0_kernel<<<(BATCH * N1 * 64) / 256, 256, 0, stream>>>(x, w_init, b_init, A);

    // Block 1 (k=50)
    conv_kernel<<<(BATCH * N1) / (4 * NPW), 256, 0, stream>>>(A, nullptr, w11, b11, Bb, K1, N1);
    conv_kernel<<<(BATCH * N1) / (4 * NPW), 256, 0, stream>>>(Bb, A, w12, b12, Cb, K1, N1);
    pool_kernel<<<(BATCH * N2 * 64) / 256, 256, 0, stream>>>(Cb, A, K1, N1, K1 / 2);

    // Block 2 (k=25)
    conv_kernel<<<(BATCH * N2) / (4 * NPW), 256, 0, stream>>>(A, nullptr, w21, b21, Bb, K2, N2);
    conv_kernel<<<(BATCH * N2) / (4 * NPW), 256, 0, stream>>>(Bb, A, w22, b22, Cb, K2, N2);
    pool_kernel<<<(BATCH * N3 * 64) / 256, 256, 0, stream>>>(Cb, A, K2, N2, K2 / 2);

    // Block 3 (k=12)
    conv_kernel<<<(BATCH * N3) / (4 * NPW), 256, 0, stream>>>(A, nullptr, w31, b31, Bb, K3, N3);
    conv_kernel<<<(BATCH * N3) / (4 * NPW), 256, 0, stream>>>(Bb, A, w32, b32, Cb, K3, N3);
    pool_kernel<<<(BATCH * 36 * 64) / 256, 256, 0, stream>>>(Cb, A, K3, N3, K3 / 2);
    // A now holds h [64, 36, 64] == flattened [64, 2304]

    // Spectral norms: G = W W^T, then 29 power iterations + sigma
    gram_kernel<<<dim3(8, 8), 256, 0, stream>>>(lw1, G1, 2304);
    gram_kernel<<<dim3(8, 8), 256, 0, stream>>>(lw2, G2, 256);
    power_kernel<<<2, 1024, 0, stream>>>(G1, G2, sg);

    // Final linears with CELU
    linear_kernel<<<dim3(4, 4), 256, 0, stream>>>(A,  lw1, lb1, sg, 0, H1, 2304);
    linear_kernel<<<dim3(4, 4), 256, 0, stream>>>(H1, lw2, lb2, sg, 1, out, 256);
}

// Round 2
// 472.833 us; speedup vs baseline: 2.1923x; 2.1923x over previous
//
#include <hip/hip_runtime.h>
#include <hip/hip_bf16.h>
#include <math.h>

// Problem constants
#define BATCH 64
#define K1 50
#define K2 25
#define K3 12
#define N1 (K1*K1)        // 2500
#define N2 (K2*K2)        // 625
#define N3 (K3*K3)        // 144
#define EPS_IN 1e-5f

#define IRT2 0.70710678118654752f
#define IRT3 0.57735026918962576f

__device__ __forceinline__ float readlane_f(float v, int l) {
    return __int_as_float(__builtin_amdgcn_readlane(__float_as_int(v), l));
}

__device__ __forceinline__ float celu1(float v) {
    return v > 0.f ? v : (__expf(v) - 1.0f);
}

// ---------------------------------------------------------------------------
// Stage 0: h0[b,n,c] = agg[b,n] * w_init[c] + b_init[c]
// ---------------------------------------------------------------------------
__global__ __launch_bounds__(256) void stage0_kernel(
    const float* __restrict__ x, const float* __restrict__ w_init,
    const float* __restrict__ b_init, float* __restrict__ out)
{
    int e = blockIdx.x * 256 + threadIdx.x;
    int c = e & 63;
    int node = e >> 6;                 // b*N1 + n
    int b = node / N1, n = node - b * N1;
    int i = n / K1, j = n - i * K1;

    // separable degree factors: deg = ri*rj, ri,rj in {2,3}
    float fi[3], fj[3];
    int ric[3], rjc[3];
    {
        int im = i - 1, ip = i + 1;
        ric[0] = im < 0 ? 0 : im;       fi[0] = im < 0 ? 0.f : ((im > 0 && im < K1-1) ? IRT3 : IRT2);
        ric[1] = i;                     fi[1] = (i > 0 && i < K1-1) ? IRT3 : IRT2;
        ric[2] = ip >= K1 ? K1-1 : ip;  fi[2] = ip >= K1 ? 0.f : ((ip > 0 && ip < K1-1) ? IRT3 : IRT2);
        int jm = j - 1, jp = j + 1;
        rjc[0] = jm < 0 ? 0 : jm;       fj[0] = jm < 0 ? 0.f : ((jm > 0 && jm < K1-1) ? IRT3 : IRT2);
        rjc[1] = j;                     fj[1] = (j > 0 && j < K1-1) ? IRT3 : IRT2;
        rjc[2] = jp >= K1 ? K1-1 : jp;  fj[2] = jp >= K1 ? 0.f : ((jp > 0 && jp < K1-1) ? IRT3 : IRT2);
    }
    float rsdn = fi[1] * fj[1];
    int rowb = b * N1;

    float agg = 0.f;
#pragma unroll
    for (int di = 0; di < 3; ++di) {
        float wr = rsdn * fi[di];
        int rb = rowb + ric[di] * K1;
#pragma unroll
        for (int dj = 0; dj < 3; ++dj) {
            agg = fmaf(wr * fj[dj], x[rb + rjc[dj]], agg);
        }
    }
    out[e] = fmaf(agg, w_init[c], b_init[c]);
}

// ---------------------------------------------------------------------------
// Fused GCNConv + InstanceNorm + (optional residual) + CELU.
// One wave per node, NPW nodes per wave. Lane = channel.
// ---------------------------------------------------------------------------
#define NPW 8
template<int KK>
__global__ __launch_bounds__(256, 4) void conv_kernel(
    const float* __restrict__ xin, const float* __restrict__ resid,
    const float* __restrict__ Wm, const float* __restrict__ bias,
    float* __restrict__ out)
{
    constexpr int NN = KK * KK;
    const int lane = threadIdx.x & 63;
    const int w = threadIdx.x >> 6;

    float wreg[64];
#pragma unroll
    for (int ci = 0; ci < 64; ++ci) wreg[ci] = Wm[ci * 64 + lane];
    // pin W in VGPRs: forbid rematerialization of the loads
#pragma unroll
    for (int ci = 0; ci < 64; ++ci) asm volatile("" : "+v"(wreg[ci]));
    float bz = bias[lane];

    int base = blockIdx.x * (4 * NPW);
#pragma unroll 1
    for (int it = 0; it < NPW; ++it) {
        int node = base + it * 4 + w;       // exact grid: always valid
        int b = node / NN;                  // const divisor -> magic mul
        int n = node - b * NN;
        int i = n / KK;
        int j = n - i * KK;

        float fi[3], fj[3];
        int ric[3], rjc[3];
        {
            int im = i - 1, ip = i + 1;
            ric[0] = im < 0 ? 0 : im;       fi[0] = im < 0 ? 0.f : ((im > 0 && im < KK-1) ? IRT3 : IRT2);
            ric[1] = i;                     fi[1] = (i > 0 && i < KK-1) ? IRT3 : IRT2;
            ric[2] = ip >= KK ? KK-1 : ip;  fi[2] = ip >= KK ? 0.f : ((ip > 0 && ip < KK-1) ? IRT3 : IRT2);
            int jm = j - 1, jp = j + 1;
            rjc[0] = jm < 0 ? 0 : jm;       fj[0] = jm < 0 ? 0.f : ((jm > 0 && jm < KK-1) ? IRT3 : IRT2);
            rjc[1] = j;                     fj[1] = (j > 0 && j < KK-1) ? IRT3 : IRT2;
            rjc[2] = jp >= KK ? KK-1 : jp;  fj[2] = jp >= KK ? 0.f : ((jp > 0 && jp < KK-1) ? IRT3 : IRT2);
        }
        float rsdn = fi[1] * fj[1];

        int rowb[3], colo[3];
#pragma unroll
        for (int t = 0; t < 3; ++t) rowb[t] = ((node - n) + ric[t] * KK) * 64 + lane;
#pragma unroll
        for (int t = 0; t < 3; ++t) colo[t] = rjc[t] * 64;

        float s = 0.f;
#pragma unroll
        for (int di = 0; di < 3; ++di) {
            float wr = rsdn * fi[di];
#pragma unroll
            for (int dj = 0; dj < 3; ++dj) {
                s = fmaf(wr * fj[dj], xin[rowb[di] + colo[dj]], s);
            }
        }

        // 64x64 matmul: acc[co=lane] = sum_ci s[ci] * W[ci][co]
        float acc = 0.f;
#pragma unroll
        for (int ci = 0; ci < 64; ++ci)
            acc = fmaf(readlane_f(s, ci), wreg[ci], acc);

        float t = acc + bz;

        // InstanceNorm over 64 channels
        float s1 = t;
#pragma unroll
        for (int off = 32; off; off >>= 1) s1 += __shfl_xor(s1, off, 64);
        float mean = s1 * (1.0f / 64.0f);
        float d = t - mean;
        float s2 = d * d;
#pragma unroll
        for (int off = 32; off; off >>= 1) s2 += __shfl_xor(s2, off, 64);
        float var = s2 * (1.0f / 64.0f);
        float val = d * __frsqrt_rn(var + EPS_IN);

        if (resid) val += resid[node * 64 + lane];
        out[node * 64 + lane] = celu1(val);
    }
}

// ---------------------------------------------------------------------------
// 2x2 max pool (truncating)
// ---------------------------------------------------------------------------
template<int KK>
__global__ __launch_bounds__(256) void pool_kernel(
    const float* __restrict__ xin, float* __restrict__ out)
{
    constexpr int NIN = KK * KK;
    constexpr int KH = KK / 2;
    constexpr int P = KH * KH;
    int e = blockIdx.x * 256 + threadIdx.x;
    int c = e & 63;
    int np = e >> 6;
    int b = np / P, p = np - b * P;
    int pi = p / KH, pj = p - pi * KH;
    int basei = (b * NIN + (2 * pi) * KK + 2 * pj) * 64 + c;
    float v0 = xin[basei];
    float v1 = xin[basei + 64];
    float v2 = xin[basei + KK * 64];
    float v3 = xin[basei + KK * 64 + 64];
    out[e] = fmaxf(fmaxf(v0, v1), fmaxf(v2, v3));
}

// ---------------------------------------------------------------------------
// Partial Gram: Gp[s] = W[:, ks..ks+kchunk) @ W[:, ...].T   (W is [256, K])
// grid (8,8,S), block 256, 32x32 tile per block.
// ---------------------------------------------------------------------------
__global__ __launch_bounds__(256) void gram_kernel(
    const float* __restrict__ W, float* __restrict__ Gp, int K, int kchunk)
{
    __shared__ float As[32][33];
    __shared__ float Bs[32][33];
    int ti = blockIdx.x * 32;
    int tj = blockIdx.y * 32;
    int s = blockIdx.z;
    int k0s = s * kchunk;
    int tx = threadIdx.x & 15, ty = threadIdx.x >> 4;
    float a00 = 0.f, a01 = 0.f, a10 = 0.f, a11 = 0.f;
    for (int k0 = k0s; k0 < k0s + kchunk; k0 += 32) {
        for (int l = threadIdx.x; l < 1024; l += 256) {
            int r = l >> 5, cc = l & 31;
            As[r][cc] = W[(ti + r) * K + k0 + cc];
            Bs[r][cc] = W[(tj + r) * K + k0 + cc];
        }
        __syncthreads();
#pragma unroll
        for (int kk = 0; kk < 32; ++kk) {
            float a0 = As[ty][kk],      a1 = As[ty + 16][kk];
            float b0 = Bs[tx][kk],      b1 = Bs[tx + 16][kk];
            a00 = fmaf(a0, b0, a00); a01 = fmaf(a0, b1, a01);
            a10 = fmaf(a1, b0, a10); a11 = fmaf(a1, b1, a11);
        }
        __syncthreads();
    }
    float* G = Gp + s * 65536;
    G[(ti + ty) * 256 + tj + tx]           = a00;
    G[(ti + ty) * 256 + tj + tx + 16]      = a01;
    G[(ti + ty + 16) * 256 + tj + tx]      = a10;
    G[(ti + ty + 16) * 256 + tj + tx + 16] = a11;
}

__global__ __launch_bounds__(256) void gram_reduce(
    const float* __restrict__ Gp1, const float* __restrict__ Gp2,
    float* __restrict__ G1, float* __restrict__ G2)
{
    int idx = blockIdx.x * 256 + threadIdx.x;
    if (idx < 65536) {
        float a = 0.f;
#pragma unroll
        for (int s = 0; s < 6; ++s) a += Gp1[s * 65536 + idx];
        G1[idx] = a;
    } else {
        int jx = idx - 65536;
        G2[jx] = Gp2[jx] + Gp2[65536 + jx];
    }
}

// ---------------------------------------------------------------------------
// Power iteration on symmetric G (256x256): u <- (G u) * 0.5 (deferred norm,
// scale-invariant final formula). sigma = ||G u|| / sqrt(u.G u).
// grid 2, block 1024. Thread (i=tid&255, q=tid>>8) holds G[64q..64q+63, i].
// ---------------------------------------------------------------------------
__global__ __launch_bounds__(1024, 4) void power_kernel(
    const float* __restrict__ G1, const float* __restrict__ G2,
    float* __restrict__ sig)
{
    const float* G = (blockIdx.x == 0) ? G1 : G2;
    __shared__ float u[256];
    __shared__ float red[1024];
    __shared__ float gu_s[256];
    int tid = threadIdx.x, q = tid >> 8;

    float g[64];
#pragma unroll
    for (int m = 0; m < 64; ++m) g[m] = G[(q * 64 + m) * 256 + (tid & 255)];
#pragma unroll
    for (int m = 0; m < 64; ++m) asm volatile("" : "+v"(g[m]));
    if (tid < 256) u[tid] = 0.0625f;
    __syncthreads();

    for (int it = 0; it < 29; ++it) {
        float p = 0.f;
#pragma unroll
        for (int m = 0; m < 64; ++m) p = fmaf(g[m], u[q * 64 + m], p);
        red[tid] = p;
        __syncthreads();
        if (tid < 256)
            u[tid] = (red[tid] + red[tid + 256] + red[tid + 512] + red[tid + 768]) * 0.5f;
        __syncthreads();
    }

    // final: a = ||G u||^2, b = u . (G u); sigma = sqrt(a/b)
    float p = 0.f;
#pragma unroll
    for (int m = 0; m < 64; ++m) p = fmaf(g[m], u[q * 64 + m], p);
    red[tid] = p;
    __syncthreads();
    if (tid < 256) {
        gu_s[tid] = red[tid] + red[tid + 256] + red[tid + 512] + red[tid + 768];
    }
    __syncthreads();
    if (tid < 64) {
        float a = 0.f, bs = 0.f;
        for (int z = tid; z < 256; z += 64) {
            float v = gu_s[z];
            a = fmaf(v, v, a);
            bs = fmaf(u[z], v, bs);
        }
#pragma unroll
        for (int off = 32; off; off >>= 1) {
            a  += __shfl_xor(a, off, 64);
            bs += __shfl_xor(bs, off, 64);
        }
        if (tid == 0) sig[blockIdx.x] = sqrtf(a / bs);
    }
}

// ---------------------------------------------------------------------------
// Split-K linear partials: part[s][b][o] = X[b, ks..] . Wt[o, ks..]
// X [64,K], Wt [256,K]. grid (4 o-tiles, 4 b-tiles, S), block 256.
// ---------------------------------------------------------------------------
__global__ __launch_bounds__(256) void linear_part(
    const float* __restrict__ X, const float* __restrict__ Wt,
    float* __restrict__ part, int K, int kchunk)
{
    __shared__ float wl[64 * 129];
    __shared__ float hl[16 * 128];
    int o0 = blockIdx.x * 64, b0 = blockIdx.y * 16;
    int s = blockIdx.z;
    int k0s = s * kchunk;
    int t = threadIdx.x, o = t & 63, br = t >> 6;
    float acc[4] = {0.f, 0.f, 0.f, 0.f};

    for (int k0 = k0s; k0 < k0s + kchunk; k0 += 128) {
        for (int l = t; l < 64 * 128; l += 256) {
            int r = l >> 7, cc = l & 127;
            wl[r * 129 + cc] = Wt[(o0 + r) * K + k0 + cc];
        }
        for (int l = t; l < 16 * 128; l += 256) {
            int r = l >> 7, cc = l & 127;
            hl[r * 128 + cc] = X[(b0 + r) * K + k0 + cc];
        }
        __syncthreads();
        for (int kk = 0; kk < 128; ++kk) {
            float wv = wl[o * 129 + kk];
#pragma unroll
            for (int r = 0; r < 4; ++r)
                acc[r] = fmaf(hl[(br + (r << 2)) * 128 + kk], wv, acc[r]);
        }
        __syncthreads();
    }
#pragma unroll
    for (int r = 0; r < 4; ++r)
        part[(s * 64 + b0 + br + (r << 2)) * 256 + o0 + o] = acc[r];
}

__global__ __launch_bounds__(256) void linear_epi(
    const float* __restrict__ part, const float* __restrict__ bias,
    const float* __restrict__ sig, int sidx, int S, float* __restrict__ out)
{
    int idx = blockIdx.x * 256 + threadIdx.x;   // b*256 + o
    float a = 0.f;
    for (int s = 0; s < S; ++s) a += part[s * 16384 + idx];
    int o = idx & 255;
    float v = a / sig[sidx] + bias[o];
    out[idx] = celu1(v);
}

// ---------------------------------------------------------------------------
extern "C" void kernel_launch(void* const* d_in, const int* in_sizes, int n_in,
                              void* d_out, int out_size, void* d_ws, size_t ws_size,
                              hipStream_t stream)
{
    const float* x      = (const float*)d_in[0];
    const float* w_init = (const float*)d_in[1];
    const float* b_init = (const float*)d_in[2];
    const float* w11 = (const float*)d_in[3];  const float* b11 = (const float*)d_in[4];
    const float* w12 = (const float*)d_in[5];  const float* b12 = (const float*)d_in[6];
    const float* w21 = (const float*)d_in[7];  const float* b21 = (const float*)d_in[8];
    const float* w22 = (const float*)d_in[9];  const float* b22 = (const float*)d_in[10];
    const float* w31 = (const float*)d_in[11]; const float* b31 = (const float*)d_in[12];
    const float* w32 = (const float*)d_in[13]; const float* b32 = (const float*)d_in[14];
    const float* lw1 = (const float*)d_in[15]; const float* lb1 = (const float*)d_in[16];
    const float* lw2 = (const float*)d_in[17]; const float* lb2 = (const float*)d_in[18];
    float* out = (float*)d_out;

    char* ws = (char*)d_ws;
    const size_t SZ_BIG = (size_t)BATCH * N1 * 64 * sizeof(float);   // 40,960,000 B
    float* A  = (float*)ws;
    float* Bb = (float*)(ws + SZ_BIG);
    float* Cb = (float*)(ws + 2 * SZ_BIG);
    // small buffers live in Bb's region (free once convs finish)
    float* G1    = Bb;
    float* G2    = G1 + 65536;
    float* Gp1   = G2 + 65536;           // 6 * 65536
    float* Gp2   = Gp1 + 6 * 65536;      // 2 * 65536
    float* sg    = Gp2 + 2 * 65536;      // 2
    float* part1 = sg + 16;              // 6 * 16384
    float* part2 = part1 + 6 * 16384;    // 2 * 16384
    float* H1    = part2 + 2 * 16384;    // 16384

    // Stage 0: init GCN  x -> A  [B, 2500, 64]
    stage0_kernel<<<(BATCH * N1 * 64) / 256, 256, 0, stream>>>(x, w_init, b_init, A);

    // Block 1 (k=50)
    conv_kernel<K1><<<(BATCH * N1) / 32, 256, 0, stream>>>(A, nullptr, w11, b11, Bb);
    conv_kernel<K1><<<(BATCH * N1) / 32, 256, 0, stream>>>(Bb, A, w12, b12, Cb);
    pool_kernel<K1><<<(BATCH * N2 * 64) / 256, 256, 0, stream>>>(Cb, A);

    // Block 2 (k=25)
    conv_kernel<K2><<<(BATCH * N2) / 32, 256, 0, stream>>>(A, nullptr, w21, b21, Bb);
    conv_kernel<K2><<<(BATCH * N2) / 32, 256, 0, stream>>>(Bb, A, w22, b22, Cb);
    pool_kernel<K2><<<(BATCH * N3 * 64) / 256, 256, 0, stream>>>(Cb, A);

    // Block 3 (k=12)
    conv_kernel<K3><<<(BATCH * N3) / 32, 256, 0, stream>>>(A, nullptr, w31, b31, Bb);
    conv_kernel<K3><<<(BATCH * N3) / 32, 256, 0, stream>>>(Bb, A, w32, b32, Cb);
    pool_kernel<K3><<<(BATCH * 36 * 64) / 256, 256, 0, stream>>>(Cb, A);
    // A now holds h [64, 36, 64] == flattened [64, 2304]

    // Spectral norms
    gram_kernel<<<dim3(8, 8, 6), 256, 0, stream>>>(lw1, Gp1, 2304, 384);
    gram_kernel<<<dim3(8, 8, 2), 256, 0, stream>>>(lw2, Gp2, 256, 128);
    gram_reduce<<<512, 256, 0, stream>>>(Gp1, Gp2, G1, G2);
    power_kernel<<<2, 1024, 0, stream>>>(G1, G2, sg);

    // Final linears with CELU (split-K partials + epilogue)
    linear_part<<<dim3(4, 4, 6), 256, 0, stream>>>(A,  lw1, part1, 2304, 384);
    linear_epi<<<64, 256, 0, stream>>>(part1, lb1, sg, 0, 6, H1);
    linear_part<<<dim3(4, 4, 2), 256, 0, stream>>>(H1, lw2, part2, 256, 128);
    linear_epi<<<64, 256, 0, stream>>>(part2, lb2, sg, 1, 2, out);
}

// Round 3
// 390.826 us; speedup vs baseline: 2.6523x; 1.2098x over previous
//
#include <hip/hip_runtime.h>
#include <hip/hip_bf16.h>
#include <math.h>

// Problem constants
#define BATCH 64
#define K1 50
#define K2 25
#define K3 12
#define N1 (K1*K1)        // 2500
#define N2 (K2*K2)        // 625
#define N3 (K3*K3)        // 144
#define EPS_IN 1e-5f

#define IRT2 0.70710678118654752f
#define IRT3 0.57735026918962576f

typedef __bf16 bf16x8 __attribute__((ext_vector_type(8)));
typedef float  f32x4  __attribute__((ext_vector_type(4)));

__device__ __forceinline__ float celu1(float v) {
    return v > 0.f ? v : (__expf(v) - 1.0f);
}

// ---------------------------------------------------------------------------
// Stage 0: agg[b,n] = 9-point symmetric-normalized stencil over x [B, 2500]
// (the rank-1 h0 = agg*w_init + b_init is never materialized)
// ---------------------------------------------------------------------------
__global__ __launch_bounds__(256) void stage0_agg(
    const float* __restrict__ x, float* __restrict__ agg)
{
    int node = blockIdx.x * 256 + threadIdx.x;   // 160000 exact
    int b = node / N1, n = node - b * N1;
    int i = n / K1, j = n - i * K1;

    float fi[3], fj[3];
    int ric[3], rjc[3];
    {
        int im = i - 1, ip = i + 1;
        ric[0] = im < 0 ? 0 : im;       fi[0] = im < 0 ? 0.f : ((im > 0 && im < K1-1) ? IRT3 : IRT2);
        ric[1] = i;                     fi[1] = (i > 0 && i < K1-1) ? IRT3 : IRT2;
        ric[2] = ip >= K1 ? K1-1 : ip;  fi[2] = ip >= K1 ? 0.f : ((ip > 0 && ip < K1-1) ? IRT3 : IRT2);
        int jm = j - 1, jp = j + 1;
        rjc[0] = jm < 0 ? 0 : jm;       fj[0] = jm < 0 ? 0.f : ((jm > 0 && jm < K1-1) ? IRT3 : IRT2);
        rjc[1] = j;                     fj[1] = (j > 0 && j < K1-1) ? IRT3 : IRT2;
        rjc[2] = jp >= K1 ? K1-1 : jp;  fj[2] = jp >= K1 ? 0.f : ((jp > 0 && jp < K1-1) ? IRT3 : IRT2);
    }
    float rsdn = fi[1] * fj[1];
    int rowb = b * N1;

    float s = 0.f;
#pragma unroll
    for (int di = 0; di < 3; ++di) {
        float wr = rsdn * fi[di];
        int rb = rowb + ric[di] * K1;
#pragma unroll
        for (int dj = 0; dj < 3; ++dj)
            s = fmaf(wr * fj[dj], x[rb + rjc[dj]], s);
    }
    agg[node] = s;
}

// ---------------------------------------------------------------------------
// Fused GCNConv (MFMA) + InstanceNorm + residual + CELU.
// MODE: 0 = plain vector input; 1 = vector input + vector residual (aux);
//       2 = init (aux = agg scalar field, rank-1 input);
//       3 = vector input + residual reconstructed from agg (aux) rank-1.
// Block 256 = 4 waves; each wave owns 32 nodes: phase A writes its own 32
// LDS rows (no barrier), phase B does 16 mfma_f32_16x16x32_bf16, epilogue
// does instance-norm on the C-layout via 16-lane shfl_xor reductions.
// ---------------------------------------------------------------------------
template<int KK, int MODE, int NGPB>
__global__ __launch_bounds__(256, 3) void conv_kernel(
    const float* __restrict__ xin, const float* __restrict__ aux,
    const float* __restrict__ winit, const float* __restrict__ binit,
    const float* __restrict__ Wm, const float* __restrict__ bias,
    float* __restrict__ out, int Ntot)
{
    constexpr int NN = KK * KK;
    __shared__ __align__(16) __bf16 s_lds[128 * 72];   // 72 = 64 + 8 pad

    const int lane = threadIdx.x & 63;
    const int wv   = threadIdx.x >> 6;
    const int c15  = lane & 15, q = lane >> 4;

    // B fragments: W[k=ci][n=co] in bf16, k = kf*32 + q*8 + j, n = nt*16 + c15
    bf16x8 bfrag[4][2];
#pragma unroll
    for (int nt = 0; nt < 4; ++nt)
#pragma unroll
        for (int kf = 0; kf < 2; ++kf) {
            bf16x8 v;
#pragma unroll
            for (int jj = 0; jj < 8; ++jj)
                v[jj] = (__bf16)Wm[(kf * 32 + q * 8 + jj) * 64 + nt * 16 + c15];
            bfrag[nt][kf] = v;
        }
    float bias_l[4];
#pragma unroll
    for (int nt = 0; nt < 4; ++nt) bias_l[nt] = bias[nt * 16 + c15];

    float wi_l = 0.f, bi_l = 0.f;        // phase-A rank-1 factors (lane=ci)
    if (MODE == 2) { wi_l = winit[lane]; bi_l = binit[lane]; }
    float wi_e[4], bi_e[4];              // epilogue rank-1 residual factors
    if (MODE == 3) {
#pragma unroll
        for (int nt = 0; nt < 4; ++nt) {
            wi_e[nt] = winit[nt * 16 + c15];
            bi_e[nt] = binit[nt * 16 + c15];
        }
    }

    for (int gg = 0; gg < NGPB; ++gg) {
        int G0 = (blockIdx.x * NGPB + gg) * 128;

        // ---- phase A: stencil aggregate -> bf16 LDS rows (wave-private) ----
        for (int m = 0; m < 32; ++m) {
            int nl = wv * 32 + m;
            int node = G0 + nl;
            if (node >= Ntot) node = Ntot - 1;
            node = __builtin_amdgcn_readfirstlane(node);
            int b = node / NN, n = node - b * NN;
            int i = n / KK, j = n - i * KK;

            float fi[3], fj[3];
            int ric[3], rjc[3];
            {
                int im = i - 1, ip = i + 1;
                ric[0] = im < 0 ? 0 : im;       fi[0] = im < 0 ? 0.f : ((im > 0 && im < KK-1) ? IRT3 : IRT2);
                ric[1] = i;                     fi[1] = (i > 0 && i < KK-1) ? IRT3 : IRT2;
                ric[2] = ip >= KK ? KK-1 : ip;  fi[2] = ip >= KK ? 0.f : ((ip > 0 && ip < KK-1) ? IRT3 : IRT2);
                int jm = j - 1, jp = j + 1;
                rjc[0] = jm < 0 ? 0 : jm;       fj[0] = jm < 0 ? 0.f : ((jm > 0 && jm < KK-1) ? IRT3 : IRT2);
                rjc[1] = j;                     fj[1] = (j > 0 && j < KK-1) ? IRT3 : IRT2;
                rjc[2] = jp >= KK ? KK-1 : jp;  fj[2] = jp >= KK ? 0.f : ((jp > 0 && jp < KK-1) ? IRT3 : IRT2);
            }
            float rsdn = fi[1] * fj[1];

            float s;
            if (MODE == 2) {
                // rank-1 input: s = t1*w_init[c] + t2*b_init[c]
                float t1 = 0.f, t2 = 0.f;
                int rowb = b * NN;
#pragma unroll
                for (int di = 0; di < 3; ++di) {
                    float wr = rsdn * fi[di];
                    int rb = rowb + ric[di] * KK;
#pragma unroll
                    for (int dj = 0; dj < 3; ++dj) {
                        float wgt = wr * fj[dj];
                        t1 = fmaf(wgt, aux[rb + rjc[dj]], t1);
                        t2 += wgt;
                    }
                }
                s = t1 * wi_l + t2 * bi_l;
            } else {
                int rowb0 = (b * NN) * 64 + lane;
                float acc = 0.f;
#pragma unroll
                for (int di = 0; di < 3; ++di) {
                    float wr = rsdn * fi[di];
                    int rb = rowb0 + ric[di] * (KK * 64);
#pragma unroll
                    for (int dj = 0; dj < 3; ++dj)
                        acc = fmaf(wr * fj[dj], xin[rb + rjc[dj] * 64], acc);
                }
                s = acc;
            }
            s_lds[nl * 72 + lane] = (__bf16)s;
        }

        // ---- phase B: MFMA ----
        f32x4 acc[2][4];
#pragma unroll
        for (int t = 0; t < 2; ++t)
#pragma unroll
            for (int nt = 0; nt < 4; ++nt)
                acc[t][nt] = (f32x4){0.f, 0.f, 0.f, 0.f};

#pragma unroll
        for (int tile = 0; tile < 2; ++tile) {
            int r0 = wv * 32 + tile * 16 + c15;
            bf16x8 av0 = *(const bf16x8*)(s_lds + r0 * 72 + q * 8);
            bf16x8 av1 = *(const bf16x8*)(s_lds + r0 * 72 + 32 + q * 8);
#pragma unroll
            for (int nt = 0; nt < 4; ++nt) {
                acc[tile][nt] = __builtin_amdgcn_mfma_f32_16x16x32_bf16(av0, bfrag[nt][0], acc[tile][nt], 0, 0, 0);
                acc[tile][nt] = __builtin_amdgcn_mfma_f32_16x16x32_bf16(av1, bfrag[nt][1], acc[tile][nt], 0, 0, 0);
            }
        }

        // ---- epilogue: bias -> inorm -> resid -> celu -> store ----
#pragma unroll
        for (int tile = 0; tile < 2; ++tile) {
            float tm[4][4];   // [nt][reg]
#pragma unroll
            for (int nt = 0; nt < 4; ++nt)
#pragma unroll
                for (int r = 0; r < 4; ++r)
                    tm[nt][r] = acc[tile][nt][r] + bias_l[nt];

#pragma unroll
            for (int r = 0; r < 4; ++r) {
                float p = tm[0][r] + tm[1][r] + tm[2][r] + tm[3][r];
#pragma unroll
                for (int off = 1; off < 16; off <<= 1) p += __shfl_xor(p, off, 64);
                float mean = p * (1.0f / 64.0f);
                float vs = 0.f;
#pragma unroll
                for (int nt = 0; nt < 4; ++nt) {
                    float d = tm[nt][r] - mean;
                    vs = fmaf(d, d, vs);
                }
#pragma unroll
                for (int off = 1; off < 16; off <<= 1) vs += __shfl_xor(vs, off, 64);
                float rstd = __frsqrt_rn(vs * (1.0f / 64.0f) + EPS_IN);

                int node = G0 + wv * 32 + tile * 16 + q * 4 + r;
                if (node < Ntot) {
                    int base = node * 64 + c15;
                    float av = 0.f;
                    if (MODE == 3) av = aux[node];
#pragma unroll
                    for (int nt = 0; nt < 4; ++nt) {
                        float d = (tm[nt][r] - mean) * rstd;
                        if (MODE == 1) d += aux[base + nt * 16];
                        if (MODE == 3) d = fmaf(av, wi_e[nt], d + bi_e[nt]);
                        out[base + nt * 16] = celu1(d);
                    }
                }
            }
        }
    }
}

// ---------------------------------------------------------------------------
// 2x2 max pool (truncating), float4 vectorized
// ---------------------------------------------------------------------------
template<int KK>
__global__ __launch_bounds__(256) void pool_kernel(
    const float* __restrict__ xin, float* __restrict__ out)
{
    constexpr int NIN = KK * KK;
    constexpr int KH = KK / 2;
    constexpr int P = KH * KH;
    int e = blockIdx.x * 256 + threadIdx.x;   // (np, c4)
    int c = (e & 15) * 4;
    int np = e >> 4;
    int b = np / P, p = np - b * P;
    int pi = p / KH, pj = p - pi * KH;
    int basei = (b * NIN + (2 * pi) * KK + 2 * pj) * 64 + c;
    f32x4 v0 = *(const f32x4*)(xin + basei);
    f32x4 v1 = *(const f32x4*)(xin + basei + 64);
    f32x4 v2 = *(const f32x4*)(xin + basei + KK * 64);
    f32x4 v3 = *(const f32x4*)(xin + basei + KK * 64 + 64);
    f32x4 o;
#pragma unroll
    for (int z = 0; z < 4; ++z)
        o[z] = fmaxf(fmaxf(v0[z], v1[z]), fmaxf(v2[z], v3[z]));
    *(f32x4*)(out + np * 64 + c) = o;
}

// ---------------------------------------------------------------------------
// Merged partial Gram: z<6 -> W1 chunk z; z>=6 -> W2 chunk z-6.
// ---------------------------------------------------------------------------
__global__ __launch_bounds__(256) void gram_kernel(
    const float* __restrict__ W1, const float* __restrict__ W2,
    float* __restrict__ Gp1, float* __restrict__ Gp2)
{
    const float* W; float* G; int K, kc, s;
    if (blockIdx.z < 6) { W = W1; K = 2304; kc = 384; s = blockIdx.z;     G = Gp1 + s * 65536; }
    else               { W = W2; K = 256;  kc = 128; s = blockIdx.z - 6; G = Gp2 + s * 65536; }

    __shared__ float As[32][33];
    __shared__ float Bs[32][33];
    int ti = blockIdx.x * 32;
    int tj = blockIdx.y * 32;
    int k0s = s * kc;
    int tx = threadIdx.x & 15, ty = threadIdx.x >> 4;
    float a00 = 0.f, a01 = 0.f, a10 = 0.f, a11 = 0.f;
    for (int k0 = k0s; k0 < k0s + kc; k0 += 32) {
        for (int l = threadIdx.x; l < 1024; l += 256) {
            int r = l >> 5, cc = l & 31;
            As[r][cc] = W[(ti + r) * K + k0 + cc];
            Bs[r][cc] = W[(tj + r) * K + k0 + cc];
        }
        __syncthreads();
#pragma unroll
        for (int kk = 0; kk < 32; ++kk) {
            float a0 = As[ty][kk],      a1 = As[ty + 16][kk];
            float b0 = Bs[tx][kk],      b1 = Bs[tx + 16][kk];
            a00 = fmaf(a0, b0, a00); a01 = fmaf(a0, b1, a01);
            a10 = fmaf(a1, b0, a10); a11 = fmaf(a1, b1, a11);
        }
        __syncthreads();
    }
    G[(ti + ty) * 256 + tj + tx]           = a00;
    G[(ti + ty) * 256 + tj + tx + 16]      = a01;
    G[(ti + ty + 16) * 256 + tj + tx]      = a10;
    G[(ti + ty + 16) * 256 + tj + tx + 16] = a11;
}

__global__ __launch_bounds__(256) void gram_reduce(
    const float* __restrict__ Gp1, const float* __restrict__ Gp2,
    float* __restrict__ G1, float* __restrict__ G2)
{
    int idx = blockIdx.x * 256 + threadIdx.x;
    if (idx < 65536) {
        float a = 0.f;
#pragma unroll
        for (int s = 0; s < 6; ++s) a += Gp1[s * 65536 + idx];
        G1[idx] = a;
    } else {
        int jx = idx - 65536;
        G2[jx] = Gp2[jx] + Gp2[65536 + jx];
    }
}

// ---------------------------------------------------------------------------
// Power iteration on symmetric G (256x256), deferred normalization.
// ---------------------------------------------------------------------------
__global__ __launch_bounds__(1024, 4) void power_kernel(
    const float* __restrict__ G1, const float* __restrict__ G2,
    float* __restrict__ sig)
{
    const float* G = (blockIdx.x == 0) ? G1 : G2;
    __shared__ float u[256];
    __shared__ float red[1024];
    __shared__ float gu_s[256];
    int tid = threadIdx.x, q = tid >> 8;

    float g[64];
#pragma unroll
    for (int m = 0; m < 64; ++m) g[m] = G[(q * 64 + m) * 256 + (tid & 255)];
#pragma unroll
    for (int m = 0; m < 64; ++m) asm volatile("" : "+v"(g[m]));
    if (tid < 256) u[tid] = 0.0625f;
    __syncthreads();

    for (int it = 0; it < 29; ++it) {
        float p = 0.f;
#pragma unroll
        for (int m = 0; m < 64; ++m) p = fmaf(g[m], u[q * 64 + m], p);
        red[tid] = p;
        __syncthreads();
        if (tid < 256)
            u[tid] = (red[tid] + red[tid + 256] + red[tid + 512] + red[tid + 768]) * 0.5f;
        __syncthreads();
    }

    float p = 0.f;
#pragma unroll
    for (int m = 0; m < 64; ++m) p = fmaf(g[m], u[q * 64 + m], p);
    red[tid] = p;
    __syncthreads();
    if (tid < 256)
        gu_s[tid] = red[tid] + red[tid + 256] + red[tid + 512] + red[tid + 768];
    __syncthreads();
    if (tid < 64) {
        float a = 0.f, bs = 0.f;
        for (int z = tid; z < 256; z += 64) {
            float v = gu_s[z];
            a = fmaf(v, v, a);
            bs = fmaf(u[z], v, bs);
        }
#pragma unroll
        for (int off = 32; off; off >>= 1) {
            a  += __shfl_xor(a, off, 64);
            bs += __shfl_xor(bs, off, 64);
        }
        if (tid == 0) sig[blockIdx.x] = sqrtf(a / bs);
    }
}

// ---------------------------------------------------------------------------
// Split-K linear partials + epilogue
// ---------------------------------------------------------------------------
__global__ __launch_bounds__(256) void linear_part(
    const float* __restrict__ X, const float* __restrict__ Wt,
    float* __restrict__ part, int K, int kchunk)
{
    __shared__ float wl[64 * 129];
    __shared__ float hl[16 * 128];
    int o0 = blockIdx.x * 64, b0 = blockIdx.y * 16;
    int s = blockIdx.z;
    int k0s = s * kchunk;
    int t = threadIdx.x, o = t & 63, br = t >> 6;
    float acc[4] = {0.f, 0.f, 0.f, 0.f};

    for (int k0 = k0s; k0 < k0s + kchunk; k0 += 128) {
        for (int l = t; l < 64 * 128; l += 256) {
            int r = l >> 7, cc = l & 127;
            wl[r * 129 + cc] = Wt[(o0 + r) * K + k0 + cc];
        }
        for (int l = t; l < 16 * 128; l += 256) {
            int r = l >> 7, cc = l & 127;
            hl[r * 128 + cc] = X[(b0 + r) * K + k0 + cc];
        }
        __syncthreads();
        for (int kk = 0; kk < 128; ++kk) {
            float wv = wl[o * 129 + kk];
#pragma unroll
            for (int r = 0; r < 4; ++r)
                acc[r] = fmaf(hl[(br + (r << 2)) * 128 + kk], wv, acc[r]);
        }
        __syncthreads();
    }
#pragma unroll
    for (int r = 0; r < 4; ++r)
        part[(s * 64 + b0 + br + (r << 2)) * 256 + o0 + o] = acc[r];
}

__global__ __launch_bounds__(256) void linear_epi(
    const float* __restrict__ part, const float* __restrict__ bias,
    const float* __restrict__ sig, int sidx, int S, float* __restrict__ out)
{
    int idx = blockIdx.x * 256 + threadIdx.x;   // b*256 + o
    float a = 0.f;
    for (int s = 0; s < S; ++s) a += part[s * 16384 + idx];
    int o = idx & 255;
    float v = a / sig[sidx] + bias[o];
    out[idx] = celu1(v);
}

// ---------------------------------------------------------------------------
extern "C" void kernel_launch(void* const* d_in, const int* in_sizes, int n_in,
                              void* d_out, int out_size, void* d_ws, size_t ws_size,
                              hipStream_t stream)
{
    const float* x      = (const float*)d_in[0];
    const float* w_init = (const float*)d_in[1];
    const float* b_init = (const float*)d_in[2];
    const float* w11 = (const float*)d_in[3];  const float* b11 = (const float*)d_in[4];
    const float* w12 = (const float*)d_in[5];  const float* b12 = (const float*)d_in[6];
    const float* w21 = (const float*)d_in[7];  const float* b21 = (const float*)d_in[8];
    const float* w22 = (const float*)d_in[9];  const float* b22 = (const float*)d_in[10];
    const float* w31 = (const float*)d_in[11]; const float* b31 = (const float*)d_in[12];
    const float* w32 = (const float*)d_in[13]; const float* b32 = (const float*)d_in[14];
    const float* lw1 = (const float*)d_in[15]; const float* lb1 = (const float*)d_in[16];
    const float* lw2 = (const float*)d_in[17]; const float* lb2 = (const float*)d_in[18];
    float* out = (float*)d_out;

    char* ws = (char*)d_ws;
    const size_t SZ_BIG = (size_t)BATCH * N1 * 64 * sizeof(float);   // 40,960,000 B
    float* A   = (float*)ws;
    float* Bb  = (float*)(ws + SZ_BIG);
    float* Cb  = (float*)(ws + 2 * SZ_BIG);
    float* agg = (float*)(ws + 3 * SZ_BIG);          // 640 KB
    // small buffers reuse Bb's region after convs finish
    float* G1    = Bb;
    float* G2    = G1 + 65536;
    float* Gp1   = G2 + 65536;           // 6 * 65536
    float* Gp2   = Gp1 + 6 * 65536;      // 2 * 65536
    float* sg    = Gp2 + 2 * 65536;      // 2
    float* part1 = sg + 16;              // 6 * 16384
    float* part2 = part1 + 6 * 16384;    // 2 * 16384
    float* H1    = part2 + 2 * 16384;    // 16384

    // Stage 0: scalar aggregate field only (h0 is rank-1, never materialized)
    stage0_agg<<<625, 256, 0, stream>>>(x, agg);

    // Block 1 (k=50, 160000 nodes)
    conv_kernel<K1, 2, 2><<<625, 256, 0, stream>>>(agg, agg, w_init, b_init, w11, b11, Bb, BATCH * N1);
    conv_kernel<K1, 3, 2><<<625, 256, 0, stream>>>(Bb,  agg, w_init, b_init, w12, b12, Cb, BATCH * N1);
    pool_kernel<K1><<<BATCH * N2 * 64 / 4 / 256, 256, 0, stream>>>(Cb, A);

    // Block 2 (k=25, 40000 nodes)
    conv_kernel<K2, 0, 1><<<313, 256, 0, stream>>>(A,  nullptr, nullptr, nullptr, w21, b21, Bb, BATCH * N2);
    conv_kernel<K2, 1, 1><<<313, 256, 0, stream>>>(Bb, A,       nullptr, nullptr, w22, b22, Cb, BATCH * N2);
    pool_kernel<K2><<<BATCH * N3 * 64 / 4 / 256, 256, 0, stream>>>(Cb, A);

    // Block 3 (k=12, 9216 nodes)
    conv_kernel<K3, 0, 1><<<72, 256, 0, stream>>>(A,  nullptr, nullptr, nullptr, w31, b31, Bb, BATCH * N3);
    conv_kernel<K3, 1, 1><<<72, 256, 0, stream>>>(Bb, A,       nullptr, nullptr, w32, b32, Cb, BATCH * N3);
    pool_kernel<K3><<<BATCH * 36 * 64 / 4 / 256, 256, 0, stream>>>(Cb, A);
    // A now holds h [64, 36, 64] == flattened [64, 2304]

    // Spectral norms
    gram_kernel<<<dim3(8, 8, 8), 256, 0, stream>>>(lw1, lw2, Gp1, Gp2);
    gram_reduce<<<512, 256, 0, stream>>>(Gp1, Gp2, G1, G2);
    power_kernel<<<2, 1024, 0, stream>>>(G1, G2, sg);

    // Final linears with CELU (split-K partials + epilogue)
    linear_part<<<dim3(4, 4, 6), 256, 0, stream>>>(A,  lw1, part1, 2304, 384);
    linear_epi<<<64, 256, 0, stream>>>(part1, lb1, sg, 0, 6, H1);
    linear_part<<<dim3(4, 4, 2), 256, 0, stream>>>(H1, lw2, part2, 256, 128);
    linear_epi<<<64, 256, 0, stream>>>(part2, lb2, sg, 1, 2, out);
}